// Round 4
// baseline (393.285 us; speedup 1.0000x reference)
//
#include <hip/hip_runtime.h>
#include <hip/hip_bf16.h>
#include <math.h>

// Problem constants (fixed dataset: n=100, k=5, q=75, d=4096)
#define NQUERY 7500
#define NCLS   100
#define DIM    4096
#define KQ     75
#define KSUP   5
#define RPC    80        // rows per class in x = k+q
#define MPAD   7552      // 472 m-tiles * 16
#define NPAD   112       // 7 n-tiles * 16
#define CAPQ   256
#define RCAP   2048
#define EPSF   1e-8f
#define SELEM  845824    // MPAD * NPAD

typedef __attribute__((ext_vector_type(8))) short bf16x8;
typedef __attribute__((ext_vector_type(4))) short s16x4;
typedef __attribute__((ext_vector_type(4))) float f32x4;

__device__ __forceinline__ int xrow_of_query(int j) {
    return (j / KQ) * RPC + KSUP + (j % KQ);
}
__device__ __forceinline__ short bf16t(float x) {       // truncate fp32 -> bf16 bits
    union { float f; unsigned u; } v; v.f = x;
    return (short)(v.u >> 16);
}

// tile-layout offset for class-column c, dim index i:
// [nt][kstep][kq][lm][8] with nt=c>>4, lm=c&15, kstep=i>>5, kq=(i>>3)&3, e=i&7
__device__ __forceinline__ size_t tile_off(int nt, int lm, int i) {
    return (((size_t)(nt * 128 + (i >> 5)) * 4 + ((i >> 3) & 3)) * 16 + lm) * 8 + (i & 7);
}

// ---------------- K0: convert query rows to bf16 (row-major [7552][4096]) + invq
// grid 1875 x 256: one wave per query row. ssq computed on exact f32 values
// (same semantics as the old in-GEMM SSQ, now deterministic, no atomics).
__global__ __launch_bounds__(256) void k_xbf16(const float* __restrict__ x,
        short* __restrict__ Xbf, float* __restrict__ invq) {
    const int w = threadIdx.x >> 6, lane = threadIdx.x & 63;
    const int j = blockIdx.x * 4 + w;
    if (j >= NQUERY) return;
    const float* src = x + (size_t)xrow_of_query(j) * DIM + lane * 16;
    short* dst = Xbf + (size_t)j * DIM + lane * 16;
    float ssq = 0.f;
#pragma unroll
    for (int p = 0; p < 4; ++p) {           // dims p*1024 + lane*16 .. +16
        f32x4 v[4];
#pragma unroll
        for (int q = 0; q < 4; ++q) v[q] = *(const f32x4*)(src + p * 1024 + q * 4);
        bf16x8 h0, h1;
#pragma unroll
        for (int e = 0; e < 4; ++e) {
            ssq += v[0][e]*v[0][e] + v[1][e]*v[1][e] + v[2][e]*v[2][e] + v[3][e]*v[3][e];
            h0[e]     = bf16t(v[0][e]);
            h0[e + 4] = bf16t(v[1][e]);
            h1[e]     = bf16t(v[2][e]);
            h1[e + 4] = bf16t(v[3][e]);
        }
        *(bf16x8*)(dst + p * 1024)     = h0;
        *(bf16x8*)(dst + p * 1024 + 8) = h1;
    }
#pragma unroll
    for (int o = 32; o; o >>= 1) ssq += __shfl_xor(ssq, o);
    if (lane == 0) invq[j] = 1.f / fmaxf(sqrtf(ssq), EPSF);
}

// ---------------- K1: fused proto: mean -> norm (fp64) -> Phi tile layout + es + pninv
__global__ __launch_bounds__(256) void k_proto(const float* __restrict__ x,
        float* __restrict__ proto, short* __restrict__ Phi, float* __restrict__ es,
        double* __restrict__ pninv) {
    const int c = blockIdx.x, t = threadIdx.x;
    const int nt = c >> 4, lm = c & 15;
    if (c >= NCLS) {
        for (int g = t; g < 512; g += 256) {
            const int kstep = g >> 2, kq = g & 3;
            size_t o = (((size_t)(nt * 128 + kstep) * 4 + kq) * 16 + lm) * 8;
            bf16x8 z = {0,0,0,0,0,0,0,0};
            *(bf16x8*)(Phi + o) = z;
        }
        if (t == 0) es[c] = 0.f;
        return;
    }
    __shared__ double red[4];
    __shared__ float s_inv;
    const float* b0 = x + (size_t)(c * RPC) * DIM;
    float v[16];
    double ssq = 0.0;
#pragma unroll
    for (int p = 0; p < 4; ++p) {
        const int i = p * 1024 + t * 4;
        f32x4 s = {0.f, 0.f, 0.f, 0.f};
#pragma unroll
        for (int r = 0; r < KSUP; ++r)
            s += *(const f32x4*)(b0 + (size_t)r * DIM + i);
        s = s / 5.0f;
        *(f32x4*)&v[p*4] = s;
        *(f32x4*)(proto + (size_t)c*DIM + i) = s;
        ssq += (double)s[0]*s[0] + (double)s[1]*s[1]
             + (double)s[2]*s[2] + (double)s[3]*s[3];
    }
    for (int o = 32; o; o >>= 1) ssq += __shfl_down(ssq, o);
    if ((t & 63) == 0) red[t >> 6] = ssq;
    __syncthreads();
    if (t == 0) {
        double dtot = red[0] + red[1] + red[2] + red[3];
        pninv[c] = 1.0 / sqrt(dtot);
        float tot = (float)dtot;
        float inv = 1.f / fmaxf(sqrtf(tot), EPSF);
        s_inv = inv;
        es[c] = expf(tot * inv * inv);
    }
    __syncthreads();
    const float inv = s_inv;
#pragma unroll
    for (int p = 0; p < 4; ++p) {
        const int i = p * 1024 + t * 4;
        s16x4 h;
#pragma unroll
        for (int e = 0; e < 4; ++e) h[e] = bf16t(v[p*4+e] * inv);
        *(s16x4*)(Phi + tile_off(nt, lm, i)) = h;
    }
}

// ---------------- K2/K8: unified GEMM, pre-converted bf16 A, atomic epilogue.
// ROUND-4: A loads are ready bf16x8 (1 per m-tile per kstep, no convert VALU
// between load and MFMA); K-loop fully unrolled with VGPR headroom (cap 170)
// so the scheduler pipelines next-kstep A+B loads above current MFMAs.
// Per kstep: 9 VMEM loads -> 14 MFMAs. grid (59,16), 3776 waves.
template<int TNKS>
__global__ __launch_bounds__(256, 3) void k_gemm(const short* __restrict__ Xbf,
        const short* __restrict__ Bt, float* __restrict__ Sd) {
    constexpr int KST = 128 / TNKS;   // ksteps (of 32 dims) per wave
    const int bx = blockIdx.x, kz = blockIdx.y;
    const int w = threadIdx.x >> 6, lane = threadIdx.x & 63;
    const int lm = lane & 15, kq = lane >> 4;
    const int mp = bx * 4 + w;        // m-pair 0..235
    const int mt0 = mp * 2, mt1 = mt0 + 1;
    const int j0 = mt0 * 16 + lm, j1 = mt1 * 16 + lm;
    const int jc0 = j0 < NQUERY ? j0 : NQUERY - 1;
    const int jc1 = j1 < NQUERY ? j1 : NQUERY - 1;
    const short* pa0 = Xbf + (size_t)jc0 * DIM + kq * 8;
    const short* pa1 = Xbf + (size_t)jc1 * DIM + kq * 8;
    const short* pb  = Bt + (lane << 3);
    const int ks0 = kz * KST;

    f32x4 acc0[7], acc1[7];
#pragma unroll
    for (int nt = 0; nt < 7; ++nt) {
        acc0[nt] = (f32x4){0.f,0.f,0.f,0.f};
        acc1[nt] = (f32x4){0.f,0.f,0.f,0.f};
    }

#pragma unroll
    for (int s = 0; s < KST; ++s) {
        const int ks = ks0 + s;
        const bf16x8 a0 = *(const bf16x8*)(pa0 + (size_t)ks * 32);
        const bf16x8 a1 = *(const bf16x8*)(pa1 + (size_t)ks * 32);
        bf16x8 bh[7];
#pragma unroll
        for (int nt = 0; nt < 7; ++nt)
            bh[nt] = *(const bf16x8*)(pb + (((size_t)(nt * 128 + ks)) << 9));
#pragma unroll
        for (int nt = 0; nt < 7; ++nt) {
            acc0[nt] = __builtin_amdgcn_mfma_f32_16x16x32_bf16(a0, bh[nt], acc0[nt], 0, 0, 0);
            acc1[nt] = __builtin_amdgcn_mfma_f32_16x16x32_bf16(a1, bh[nt], acc1[nt], 0, 0, 0);
        }
    }

    float* s0 = Sd + (size_t)(mt0 * 16) * NPAD;
    float* s1 = Sd + (size_t)(mt1 * 16) * NPAD;
#pragma unroll
    for (int nt = 0; nt < 7; ++nt)
#pragma unroll
        for (int r = 0; r < 4; ++r) {
            atomicAdd(&s0[(size_t)(kq * 4 + r) * NPAD + nt * 16 + lm], acc0[nt][r]);
            atomicAdd(&s1[(size_t)(kq * 4 + r) * NPAD + nt * 16 + lm], acc1[nt][r]);
        }
}

// ---------------- K3: argmax/top2 + coef + per-class lists + refine-list
__global__ __launch_bounds__(256) void k_argmax(const float* __restrict__ S,
        const float* __restrict__ invq, float* __restrict__ coef,
        int* __restrict__ pos, int* __restrict__ ccnt, int* __restrict__ cls_list,
        int* __restrict__ rcnt, int* __restrict__ rlist) {
    const int j = blockIdx.x * 256 + threadIdx.x;
    if (j >= NQUERY) return;
    const float* row = S + (size_t)j * NPAD;
    float m1 = -1e30f, m2 = -1e30f;
    int i1 = 0, i2 = 0;
    for (int c = 0; c < NCLS; ++c) {
        float v = row[c];
        if (v > m1) { m2 = m1; i2 = i1; m1 = v; i1 = c; }
        else if (v > m2) { m2 = v; i2 = c; }
    }
    const float inv = invq[j];
    coef[j] = expf(m1 * inv);
    const int p = atomicAdd(&ccnt[i1], 1);
    if (p < CAPQ) { cls_list[i1 * CAPQ + p] = j; pos[j] = p; }
    else pos[j] = -1;
    if ((m1 - m2) * inv < 5e-4f) {     // bf16-hi gap noise sigma ~5e-5 -> ~10 sigma
        int rp = atomicAdd(rcnt, 1);
        if (rp < RCAP) rlist[rp] = j | (i1 << 13) | (i2 << 20);
    }
}

// ---------------- K4: fp64 refinement via proto dot (query norm cancels; pninv precomputed)
// one 256-thread block per entry (grid-strided)
__global__ __launch_bounds__(256) void k_refine(const float* __restrict__ x,
        const float* __restrict__ proto, const double* __restrict__ pninv,
        const float* __restrict__ S, const float* __restrict__ invq,
        float* __restrict__ coef, const int* __restrict__ pos,
        int* __restrict__ ccnt, int* __restrict__ cls_list,
        const int* __restrict__ rcnt, const int* __restrict__ rlist) {
    const int cnt = min(*rcnt, RCAP);
    const int t = threadIdx.x;
    __shared__ double red1[4], red2[4];
    for (int e = blockIdx.x; e < cnt; e += gridDim.x) {
        const int pk = rlist[e];
        const int j = pk & 8191, c1 = (pk >> 13) & 127, c2 = (pk >> 20) & 127;
        const float* xq = x + (size_t)xrow_of_query(j) * DIM;
        const float* p1 = proto + (size_t)c1 * DIM;
        const float* p2 = proto + (size_t)c2 * DIM;
        double d1 = 0.0, d2 = 0.0;
        for (int i = t; i < DIM; i += 256) {
            const double qv = (double)xq[i];
            d1 += (double)p1[i] * qv;
            d2 += (double)p2[i] * qv;
        }
        for (int o = 32; o; o >>= 1) { d1 += __shfl_down(d1, o); d2 += __shfl_down(d2, o); }
        if ((t & 63) == 0) { red1[t >> 6] = d1; red2[t >> 6] = d2; }
        __syncthreads();
        if (t == 0) {
            const double cos1 = (red1[0]+red1[1]+red1[2]+red1[3]) * pninv[c1];
            const double cos2 = (red2[0]+red2[1]+red2[2]+red2[3]) * pninv[c2];
            const int win = (cos2 > cos1 || (cos2 == cos1 && c2 < c1)) ? c2 : c1;
            if (win != c1) {
                coef[j] = expf(S[(size_t)j * NPAD + win] * invq[j]);
                const int pj = pos[j];
                if (pj >= 0) cls_list[c1 * CAPQ + pj] = -1;   // tombstone
                const int np = atomicAdd(&ccnt[c2], 1);
                if (np < CAPQ) cls_list[c2 * CAPQ + np] = j;
            }
        }
        __syncthreads();   // red[] reuse across grid-stride iterations
    }
}

// ---------------- K6: adapted-proto partial scatter sum (grid 8 x NCLS x 4)
// list+coef staged in LDS so row-gather iterations are independent
__global__ __launch_bounds__(128) void k_adapt(const float* __restrict__ x,
        const float* __restrict__ coef, const int* __restrict__ cls_cnt,
        const int* __restrict__ cls_list, float* __restrict__ APpart) {
    __shared__ int   s_j[CAPQ];
    __shared__ float s_cf[CAPQ];
    const int cx = blockIdx.x, c = blockIdx.y, sl = blockIdx.z;
    const int n = min(cls_cnt[c], CAPQ);
    for (int e = threadIdx.x; e < n; e += 128) {
        const int j = cls_list[c * CAPQ + e];
        s_j[e] = j;
        s_cf[e] = (j >= 0) ? coef[j] : 0.f;
    }
    __syncthreads();
    const int i0 = cx * 512 + threadIdx.x * 4;
    f32x4 acc = {0.f, 0.f, 0.f, 0.f};
    for (int e = sl; e < n; e += 4) {
        const int j = s_j[e];
        if (j >= 0) {
            const float cf = s_cf[e];
            const f32x4 v = *(const f32x4*)(x + (size_t)xrow_of_query(j) * DIM + i0);
            acc += v * cf;
        }
    }
    *(f32x4*)(APpart + (size_t)sl * NCLS * DIM + (size_t)c * DIM + i0) = acc;
}

// ---------------- K7: fused apnorm: sum 4 slices + es*proto -> norm -> APhi tile layout
__global__ __launch_bounds__(256) void k_apnorm(const float* __restrict__ APpart,
        const float* __restrict__ proto, const float* __restrict__ es,
        short* __restrict__ APhi) {
    const int c = blockIdx.x, t = threadIdx.x;
    const int nt = c >> 4, lm = c & 15;
    if (c >= NCLS) {
        for (int g = t; g < 512; g += 256) {
            const int kstep = g >> 2, kq = g & 3;
            size_t o = (((size_t)(nt * 128 + kstep) * 4 + kq) * 16 + lm) * 8;
            bf16x8 z = {0,0,0,0,0,0,0,0};
            *(bf16x8*)(APhi + o) = z;
        }
        return;
    }
    __shared__ float red[4];
    __shared__ float s_inv;
    const float e0 = es[c];
    float v[16];
    float ssq = 0.f;
#pragma unroll
    for (int p = 0; p < 4; ++p) {
        const int i = p * 1024 + t * 4;
        f32x4 s = {0.f, 0.f, 0.f, 0.f};
#pragma unroll
        for (int sl = 0; sl < 4; ++sl)
            s += *(const f32x4*)(APpart + (size_t)sl * NCLS * DIM + (size_t)c * DIM + i);
        f32x4 pr = *(const f32x4*)(proto + (size_t)c*DIM + i);
        s += pr * e0;
        *(f32x4*)&v[p*4] = s;
        ssq += s[0]*s[0] + s[1]*s[1] + s[2]*s[2] + s[3]*s[3];
    }
    for (int o = 32; o; o >>= 1) ssq += __shfl_down(ssq, o);
    if ((t & 63) == 0) red[t >> 6] = ssq;
    __syncthreads();
    if (t == 0) {
        float tot = red[0] + red[1] + red[2] + red[3];
        s_inv = 1.f / fmaxf(sqrtf(tot), EPSF);
    }
    __syncthreads();
    const float inv = s_inv;
#pragma unroll
    for (int p = 0; p < 4; ++p) {
        const int i = p * 1024 + t * 4;
        s16x4 h;
#pragma unroll
        for (int e = 0; e < 4; ++e) h[e] = bf16t(v[p*4+e] * inv);
        *(s16x4*)(APhi + tile_off(nt, lm, i)) = h;
    }
}

// ---------------- K8b: out[j,c<100] = tao * invq[j] * Ored[j,c]
__global__ __launch_bounds__(256) void k_scale(const float* __restrict__ Ored,
        const float* __restrict__ invq, const float* __restrict__ tao,
        float* __restrict__ out) {
    const int idx = blockIdx.x * 256 + threadIdx.x;   // < 187500
    if (idx >= NQUERY * 25) return;
    const int j = idx / 25, c4 = (idx % 25) * 4;
    const f32x4 s = *(const f32x4*)(Ored + (size_t)j * NPAD + c4);
    const float sc = tao[0] * invq[j];
    *(f32x4*)(out + (size_t)j * NCLS + c4) = s * sc;
}

// ---------------- workspace layout (bytes)
#define OFF_RCNT   0u
#define OFF_CCNT   256u
#define ZERO_BYTES 32768u
#define OFF_ES     32768u       // 448
#define OFF_INVQ   33280u       // 30000
#define OFF_POS    63488u       // 30000
#define OFF_COEF   93696u       // 30000
#define OFF_RLIST  123904u      // 8192
#define OFF_CLIST  132096u      // 102400
#define OFF_PNINV  234496u      // 800 (doubles)
#define OFF_PROTO  235520u      // 1,638,400
#define OFF_PHI    1873920u     // 917,504 (tile layout)
#define OFF_APHI   2791424u     // 917,504
#define OFF_SRED   3708928u     // 3,383,296 (atomic accumulator, GEMM1)
#define OFF_ORED   7092224u     // 3,383,296 (atomic accumulator, GEMM2)
#define OFF_APPART 10475520u    // 4 x 1,638,400
#define OFF_XBF    17029120u    // 7552 x 4096 x 2 = 61,865,984 (bf16 queries)

extern "C" void kernel_launch(void* const* d_in, const int* in_sizes, int n_in,
                              void* d_out, int out_size, void* d_ws, size_t ws_size,
                              hipStream_t stream) {
    const float* x   = (const float*)d_in[0];
    const float* tao = (const float*)d_in[1];
    char* ws = (char*)d_ws;

    int*    rcnt    = (int*)   (ws + OFF_RCNT);
    int*    ccnt    = (int*)   (ws + OFF_CCNT);
    float*  es      = (float*) (ws + OFF_ES);
    float*  invq    = (float*) (ws + OFF_INVQ);
    int*    pos     = (int*)   (ws + OFF_POS);
    float*  coef    = (float*) (ws + OFF_COEF);
    int*    rlist   = (int*)   (ws + OFF_RLIST);
    int*    clist   = (int*)   (ws + OFF_CLIST);
    double* pninv   = (double*)(ws + OFF_PNINV);
    float*  proto   = (float*) (ws + OFF_PROTO);
    short*  Phi     = (short*) (ws + OFF_PHI);
    short*  APhi    = (short*) (ws + OFF_APHI);
    float*  Sred    = (float*) (ws + OFF_SRED);
    float*  Ored    = (float*) (ws + OFF_ORED);
    float*  APpart  = (float*) (ws + OFF_APPART);
    short*  Xbf     = (short*) (ws + OFF_XBF);

    hipMemsetAsync(ws, 0, ZERO_BYTES, stream);
    hipMemsetAsync(ws + OFF_SRED, 0, 2u * 3383296u, stream);   // Sred + Ored

    k_xbf16 <<<1875, 256, 0, stream>>>(x, Xbf, invq);
    k_proto <<<NPAD, 256, 0, stream>>>(x, proto, Phi, es, pninv);
    k_gemm<16><<<dim3(59, 16), 256, 0, stream>>>(Xbf, Phi, Sred);
    k_argmax <<<30, 256, 0, stream>>>(Sred, invq, coef, pos, ccnt, clist, rcnt, rlist);
    k_refine <<<512, 256, 0, stream>>>(x, proto, pninv, Sred, invq, coef, pos, ccnt, clist, rcnt, rlist);
    k_adapt  <<<dim3(8, NCLS, 4), 128, 0, stream>>>(x, coef, ccnt, clist, APpart);
    k_apnorm <<<NPAD, 256, 0, stream>>>(APpart, proto, es, APhi);
    k_gemm<16><<<dim3(59, 16), 256, 0, stream>>>(Xbf, APhi, Ored);
    k_scale  <<<733, 256, 0, stream>>>(Ored, invq, tao, (float*)d_out);
}

// Round 6
// 378.315 us; speedup vs baseline: 1.0396x; 1.0396x over previous
//
#include <hip/hip_runtime.h>
#include <hip/hip_cooperative_groups.h>
#include <hip/hip_bf16.h>
#include <math.h>

namespace cg = cooperative_groups;

// Problem constants (fixed dataset: n=100, k=5, q=75, d=4096)
#define NQUERY 7500
#define NCLS   100
#define DIM    4096
#define KQ     75
#define KSUP   5
#define RPC    80        // rows per class in x = k+q
#define MPAD   7552      // 472 m-tiles * 16
#define NPAD   112       // 7 n-tiles * 16
#define CAPQ   256
#define RCAP   2048
#define EPSF   1e-8f

typedef __attribute__((ext_vector_type(8))) short bf16x8;
typedef __attribute__((ext_vector_type(4))) short s16x4;
typedef __attribute__((ext_vector_type(4))) float f32x4;

__device__ __forceinline__ int xrow_of_query(int j) {
    return (j / KQ) * RPC + KSUP + (j % KQ);
}
__device__ __forceinline__ short bf16t(float x) {       // truncate fp32 -> bf16 bits
    union { float f; unsigned u; } v; v.f = x;
    return (short)(v.u >> 16);
}
// tile-layout offset for class-column c, dim index i:
// [nt][kstep][kq][lm][8] with nt=c>>4, lm=c&15, kstep=i>>5, kq=(i>>3)&3, e=i&7
__device__ __forceinline__ size_t tile_off(int nt, int lm, int i) {
    return (((size_t)(nt * 128 + (i >> 5)) * 4 + ((i >> 3) & 3)) * 16 + lm) * 8 + (i & 7);
}

// ---------------- workspace layout (bytes)
#define OFF_RCNT   0u
#define OFF_CCNT   256u
#define OFF_NQ2    1792u        // 30000
#define ZERO_BYTES 32768u
#define OFF_ES     32768u       // 448
#define OFF_INVQ   33280u       // 30000
#define OFF_POS    63488u       // 30000
#define OFF_COEF   93696u       // 30000
#define OFF_RLIST  123904u      // 8192
#define OFF_CLIST  132096u      // 102400
#define OFF_PNINV  234496u      // 800 (doubles)
#define OFF_PROTO  235520u      // 1,638,400
#define OFF_PHI    1873920u     // 917,504 (tile layout)
#define OFF_APHI   2791424u     // 917,504
#define OFF_SRED   3708928u     // 3,383,296 (atomic accumulator, GEMM1)
#define OFF_ORED   7092224u     // 3,383,296 (atomic accumulator, GEMM2)
#define OFF_APPART 10475520u    // 4 x 1,638,400

// ================= stage bodies (shared by mega kernel and fallback wrappers).
// All grid-stride on blockIdx.x/gridDim.x so any real grid size works.

// stage: proto mean -> fp64 norm -> Phi tiles + es + pninv  (virtual grid 112)
__device__ __forceinline__ void stage_proto(const float* __restrict__ x,
        float* __restrict__ proto, short* __restrict__ Phi, float* __restrict__ es,
        double* __restrict__ pninv) {
    __shared__ double red[4];
    __shared__ float s_inv;
    const int t = threadIdx.x;
    for (int c = blockIdx.x; c < NPAD; c += gridDim.x) {
        const int nt = c >> 4, lm = c & 15;
        if (c >= NCLS) {
            for (int g = t; g < 512; g += 256) {
                const int kstep = g >> 2, kq = g & 3;
                size_t o = (((size_t)(nt * 128 + kstep) * 4 + kq) * 16 + lm) * 8;
                bf16x8 z = {0,0,0,0,0,0,0,0};
                *(bf16x8*)(Phi + o) = z;
            }
            if (t == 0) es[c] = 0.f;
        } else {
            const float* b0 = x + (size_t)(c * RPC) * DIM;
            float v[16];
            double ssq = 0.0;
#pragma unroll
            for (int p = 0; p < 4; ++p) {
                const int i = p * 1024 + t * 4;
                f32x4 s = {0.f, 0.f, 0.f, 0.f};
#pragma unroll
                for (int r = 0; r < KSUP; ++r)
                    s += *(const f32x4*)(b0 + (size_t)r * DIM + i);
                s = s / 5.0f;
                *(f32x4*)&v[p*4] = s;
                *(f32x4*)(proto + (size_t)c*DIM + i) = s;
                ssq += (double)s[0]*s[0] + (double)s[1]*s[1]
                     + (double)s[2]*s[2] + (double)s[3]*s[3];
            }
            for (int o = 32; o; o >>= 1) ssq += __shfl_down(ssq, o);
            if ((t & 63) == 0) red[t >> 6] = ssq;
            __syncthreads();
            if (t == 0) {
                double dtot = red[0] + red[1] + red[2] + red[3];
                pninv[c] = 1.0 / sqrt(dtot);
                float tot = (float)dtot;
                float inv = 1.f / fmaxf(sqrtf(tot), EPSF);
                s_inv = inv;
                es[c] = expf(tot * inv * inv);
            }
            __syncthreads();
            const float inv = s_inv;
#pragma unroll
            for (int p = 0; p < 4; ++p) {
                const int i = p * 1024 + t * 4;
                s16x4 h;
#pragma unroll
                for (int e = 0; e < 4; ++e) h[e] = bf16t(v[p*4+e] * inv);
                *(s16x4*)(Phi + tile_off(nt, lm, i)) = h;
            }
            __syncthreads();
        }
    }
}

// stage: GEMM (32-row waves, inline bf16 convert, atomic epilogue). virtual grid 944.
__device__ __forceinline__ void gemm_stage(const float* __restrict__ x,
        const short* __restrict__ Bt, float* __restrict__ Sd,
        float* __restrict__ nq2, const bool do_ssq) {
    const int w = threadIdx.x >> 6, lane = threadIdx.x & 63;
    const int lm = lane & 15, kq = lane >> 4;
    const short* pb = Bt + (lane << 3);
#pragma unroll 1
    for (int vb = blockIdx.x; vb < 944; vb += gridDim.x) {
        const int bx = vb % 59, kz = vb / 59;
        const int mp = bx * 4 + w;        // m-pair 0..235
        const int mt0 = mp * 2, mt1 = mt0 + 1;
        const int j0 = mt0 * 16 + lm, j1 = mt1 * 16 + lm;
        const int jc0 = j0 < NQUERY ? j0 : NQUERY - 1;
        const int jc1 = j1 < NQUERY ? j1 : NQUERY - 1;
        const float* pa0 = x + (size_t)xrow_of_query(jc0) * DIM + kq * 8;
        const float* pa1 = x + (size_t)xrow_of_query(jc1) * DIM + kq * 8;
        const int ks0 = kz * 8;

        f32x4 acc0[7], acc1[7];
#pragma unroll
        for (int nt = 0; nt < 7; ++nt) {
            acc0[nt] = (f32x4){0.f,0.f,0.f,0.f};
            acc1[nt] = (f32x4){0.f,0.f,0.f,0.f};
        }
        float ssq0 = 0.f, ssq1 = 0.f;

#pragma unroll
        for (int s = 0; s < 8; ++s) {
            const int ks = ks0 + s;
            const f32x4 a00 = *(const f32x4*)(pa0 + (size_t)ks * 32);
            const f32x4 a01 = *(const f32x4*)(pa0 + (size_t)ks * 32 + 4);
            const f32x4 a10 = *(const f32x4*)(pa1 + (size_t)ks * 32);
            const f32x4 a11 = *(const f32x4*)(pa1 + (size_t)ks * 32 + 4);
            bf16x8 bh[7];
#pragma unroll
            for (int nt = 0; nt < 7; ++nt)
                bh[nt] = *(const bf16x8*)(pb + (((size_t)(nt * 128 + ks)) << 9));
            float f0[8] = {a00[0],a00[1],a00[2],a00[3],a01[0],a01[1],a01[2],a01[3]};
            float f1[8] = {a10[0],a10[1],a10[2],a10[3],a11[0],a11[1],a11[2],a11[3]};
            bf16x8 ah0, ah1;
#pragma unroll
            for (int e = 0; e < 8; ++e) {
                if (do_ssq) { ssq0 += f0[e] * f0[e]; ssq1 += f1[e] * f1[e]; }
                ah0[e] = bf16t(f0[e]);
                ah1[e] = bf16t(f1[e]);
            }
#pragma unroll
            for (int nt = 0; nt < 7; ++nt) {
                acc0[nt] = __builtin_amdgcn_mfma_f32_16x16x32_bf16(ah0, bh[nt], acc0[nt], 0, 0, 0);
                acc1[nt] = __builtin_amdgcn_mfma_f32_16x16x32_bf16(ah1, bh[nt], acc1[nt], 0, 0, 0);
            }
        }

        if (do_ssq) {
            ssq0 += __shfl_xor(ssq0, 16); ssq0 += __shfl_xor(ssq0, 32);
            ssq1 += __shfl_xor(ssq1, 16); ssq1 += __shfl_xor(ssq1, 32);
            if (kq == 0) {
                if (j0 < NQUERY) atomicAdd(&nq2[j0], ssq0);
                if (j1 < NQUERY) atomicAdd(&nq2[j1], ssq1);
            }
        }
        float* s0 = Sd + (size_t)(mt0 * 16) * NPAD;
        float* s1 = Sd + (size_t)(mt1 * 16) * NPAD;
#pragma unroll
        for (int nt = 0; nt < 7; ++nt)
#pragma unroll
            for (int r = 0; r < 4; ++r) {
                atomicAdd(&s0[(size_t)(kq * 4 + r) * NPAD + nt * 16 + lm], acc0[nt][r]);
                atomicAdd(&s1[(size_t)(kq * 4 + r) * NPAD + nt * 16 + lm], acc1[nt][r]);
            }
    }
}

// stage: argmax/top2 + invq + coef + class lists  (virtual grid 30)
__device__ __forceinline__ void stage_argmax(const float* __restrict__ S,
        const float* __restrict__ nq2, float* __restrict__ coef, float* __restrict__ invq,
        int* __restrict__ pos, int* __restrict__ ccnt, int* __restrict__ clist,
        int* __restrict__ rcnt, int* __restrict__ rlist) {
    const int t = threadIdx.x;
    for (int vb = blockIdx.x; vb < 30; vb += gridDim.x) {
        const int j = vb * 256 + t;
        if (j >= NQUERY) continue;
        const float* row = S + (size_t)j * NPAD;
        float m1 = -1e30f, m2 = -1e30f;
        int i1 = 0, i2 = 0;
        for (int c = 0; c < NCLS; ++c) {
            float v = row[c];
            if (v > m1) { m2 = m1; i2 = i1; m1 = v; i1 = c; }
            else if (v > m2) { m2 = v; i2 = c; }
        }
        const float inv = 1.f / fmaxf(sqrtf(nq2[j]), EPSF);
        invq[j] = inv;
        coef[j] = expf(m1 * inv);
        const int p = atomicAdd(&ccnt[i1], 1);
        if (p < CAPQ) { clist[i1 * CAPQ + p] = j; pos[j] = p; }
        else pos[j] = -1;
        if ((m1 - m2) * inv < 5e-4f) {   // bf16-hi gap noise sigma ~5e-5 -> ~10 sigma
            int rp = atomicAdd(rcnt, 1);
            if (rp < RCAP) rlist[rp] = j | (i1 << 13) | (i2 << 20);
        }
    }
}

// stage: fp64 refinement of borderline argmaxes (grid-strided over rcnt entries)
__device__ __forceinline__ void stage_refine(const float* __restrict__ x,
        const float* __restrict__ proto, const double* __restrict__ pninv,
        const float* __restrict__ S, const float* __restrict__ invq,
        float* __restrict__ coef, const int* __restrict__ pos,
        int* __restrict__ ccnt, int* __restrict__ clist,
        const int* __restrict__ rcnt, const int* __restrict__ rlist) {
    __shared__ double red1[4], red2[4];
    const int cnt = min(*rcnt, RCAP);
    const int t = threadIdx.x;
    for (int e = blockIdx.x; e < cnt; e += gridDim.x) {
        const int pk = rlist[e];
        const int j = pk & 8191, c1 = (pk >> 13) & 127, c2 = (pk >> 20) & 127;
        const float* xq = x + (size_t)xrow_of_query(j) * DIM;
        const float* p1 = proto + (size_t)c1 * DIM;
        const float* p2 = proto + (size_t)c2 * DIM;
        double d1 = 0.0, d2 = 0.0;
        for (int i = t; i < DIM; i += 256) {
            const double qv = (double)xq[i];
            d1 += (double)p1[i] * qv;
            d2 += (double)p2[i] * qv;
        }
        for (int o = 32; o; o >>= 1) { d1 += __shfl_down(d1, o); d2 += __shfl_down(d2, o); }
        if ((t & 63) == 0) { red1[t >> 6] = d1; red2[t >> 6] = d2; }
        __syncthreads();
        if (t == 0) {
            const double cos1 = (red1[0]+red1[1]+red1[2]+red1[3]) * pninv[c1];
            const double cos2 = (red2[0]+red2[1]+red2[2]+red2[3]) * pninv[c2];
            const int win = (cos2 > cos1 || (cos2 == cos1 && c2 < c1)) ? c2 : c1;
            if (win != c1) {
                coef[j] = expf(S[(size_t)j * NPAD + win] * invq[j]);
                const int pj = pos[j];
                if (pj >= 0) clist[c1 * CAPQ + pj] = -1;   // tombstone
                const int np = atomicAdd(&ccnt[c2], 1);
                if (np < CAPQ) clist[c2 * CAPQ + np] = j;
            }
        }
        __syncthreads();   // red[] reuse across grid-stride iterations
    }
}

// stage: adapted-proto scatter sum (virtual grid 1600 = 4 cx * 100 c * 4 sl)
__device__ __forceinline__ void stage_adapt(const float* __restrict__ x,
        const float* __restrict__ coef, const int* __restrict__ ccnt,
        const int* __restrict__ clist, float* __restrict__ APpart) {
    __shared__ int   s_j[CAPQ];
    __shared__ float s_cf[CAPQ];
    const int t = threadIdx.x;
    for (int vb = blockIdx.x; vb < 4 * NCLS * 4; vb += gridDim.x) {
        const int cx = vb & 3, c = (vb >> 2) % NCLS, sl = vb / (4 * NCLS);
        const int n = min(ccnt[c], CAPQ);
        for (int e = t; e < n; e += 256) {
            const int j = clist[c * CAPQ + e];
            s_j[e] = j;
            s_cf[e] = (j >= 0) ? coef[j] : 0.f;
        }
        __syncthreads();
        const int i0 = cx * 1024 + t * 4;
        f32x4 acc = {0.f, 0.f, 0.f, 0.f};
        for (int e = sl; e < n; e += 4) {
            const int j = s_j[e];
            if (j >= 0) {
                const float cf = s_cf[e];
                const f32x4 v = *(const f32x4*)(x + (size_t)xrow_of_query(j) * DIM + i0);
                acc += v * cf;
            }
        }
        *(f32x4*)(APpart + (size_t)sl * NCLS * DIM + (size_t)c * DIM + i0) = acc;
        __syncthreads();   // s_j/s_cf reuse across iterations
    }
}

// stage: apnorm (sum 4 slices + es*proto -> norm -> APhi tiles)  (virtual grid 112)
__device__ __forceinline__ void stage_apnorm(const float* __restrict__ APpart,
        const float* __restrict__ proto, const float* __restrict__ es,
        short* __restrict__ APhi) {
    __shared__ float red[4];
    __shared__ float s_inv;
    const int t = threadIdx.x;
    for (int c = blockIdx.x; c < NPAD; c += gridDim.x) {
        const int nt = c >> 4, lm = c & 15;
        if (c >= NCLS) {
            for (int g = t; g < 512; g += 256) {
                const int kstep = g >> 2, kq = g & 3;
                size_t o = (((size_t)(nt * 128 + kstep) * 4 + kq) * 16 + lm) * 8;
                bf16x8 z = {0,0,0,0,0,0,0,0};
                *(bf16x8*)(APhi + o) = z;
            }
        } else {
            const float e0 = es[c];
            float v[16];
            float ssq = 0.f;
#pragma unroll
            for (int p = 0; p < 4; ++p) {
                const int i = p * 1024 + t * 4;
                f32x4 s = {0.f, 0.f, 0.f, 0.f};
#pragma unroll
                for (int sl = 0; sl < 4; ++sl)
                    s += *(const f32x4*)(APpart + (size_t)sl * NCLS * DIM + (size_t)c * DIM + i);
                f32x4 pr = *(const f32x4*)(proto + (size_t)c*DIM + i);
                s += pr * e0;
                *(f32x4*)&v[p*4] = s;
                ssq += s[0]*s[0] + s[1]*s[1] + s[2]*s[2] + s[3]*s[3];
            }
            for (int o = 32; o; o >>= 1) ssq += __shfl_down(ssq, o);
            if ((t & 63) == 0) red[t >> 6] = ssq;
            __syncthreads();
            if (t == 0) {
                float tot = red[0] + red[1] + red[2] + red[3];
                s_inv = 1.f / fmaxf(sqrtf(tot), EPSF);
            }
            __syncthreads();
            const float inv = s_inv;
#pragma unroll
            for (int p = 0; p < 4; ++p) {
                const int i = p * 1024 + t * 4;
                s16x4 h;
#pragma unroll
                for (int e = 0; e < 4; ++e) h[e] = bf16t(v[p*4+e] * inv);
                *(s16x4*)(APhi + tile_off(nt, lm, i)) = h;
            }
            __syncthreads();
        }
    }
}

// stage: out = tao * invq * Ored  (virtual grid 733)
__device__ __forceinline__ void stage_scale(const float* __restrict__ Ored,
        const float* __restrict__ invq, const float* __restrict__ tao,
        float* __restrict__ out) {
    const int t = threadIdx.x;
    for (int vb = blockIdx.x; vb < 733; vb += gridDim.x) {
        const int idx = vb * 256 + t;
        if (idx < NQUERY * 25) {
            const int j = idx / 25, c4 = (idx % 25) * 4;
            const f32x4 s = *(const f32x4*)(Ored + (size_t)j * NPAD + c4);
            const float sc = tao[0] * invq[j];
            *(f32x4*)(out + (size_t)j * NCLS + c4) = s * sc;
        }
    }
}

// ================= cooperative mega kernel (all stages, grid-wide syncs) =====
#define FENCE_SYNC() do { __threadfence_system(); grid.sync(); __threadfence_system(); } while (0)

__global__ __launch_bounds__(256) void mega(const float* __restrict__ x,
        const float* __restrict__ tao, float* __restrict__ out, char* __restrict__ ws) {
    int*    rcnt    = (int*)   (ws + OFF_RCNT);
    int*    ccnt    = (int*)   (ws + OFF_CCNT);
    float*  nq2     = (float*) (ws + OFF_NQ2);
    float*  es      = (float*) (ws + OFF_ES);
    float*  invq    = (float*) (ws + OFF_INVQ);
    int*    pos     = (int*)   (ws + OFF_POS);
    float*  coef    = (float*) (ws + OFF_COEF);
    int*    rlist   = (int*)   (ws + OFF_RLIST);
    int*    clist   = (int*)   (ws + OFF_CLIST);
    double* pninv   = (double*)(ws + OFF_PNINV);
    float*  proto   = (float*) (ws + OFF_PROTO);
    short*  Phi     = (short*) (ws + OFF_PHI);
    short*  APhi    = (short*) (ws + OFF_APHI);
    float*  Sred    = (float*) (ws + OFF_SRED);
    float*  Ored    = (float*) (ws + OFF_ORED);
    float*  APpart  = (float*) (ws + OFF_APPART);

    cg::grid_group grid = cg::this_grid();

    stage_proto(x, proto, Phi, es, pninv);
    FENCE_SYNC();
    gemm_stage(x, Phi, Sred, nq2, true);
    FENCE_SYNC();
    stage_argmax(Sred, nq2, coef, invq, pos, ccnt, clist, rcnt, rlist);
    FENCE_SYNC();
    stage_refine(x, proto, pninv, Sred, invq, coef, pos, ccnt, clist, rcnt, rlist);
    FENCE_SYNC();
    stage_adapt(x, coef, ccnt, clist, APpart);
    FENCE_SYNC();
    stage_apnorm(APpart, proto, es, APhi);
    FENCE_SYNC();
    gemm_stage(x, APhi, Ored, nq2, false);
    FENCE_SYNC();
    stage_scale(Ored, invq, tao, out);
}

// ================= fallback wrappers (ordinary kernel chain, = round-2 path) =
__global__ __launch_bounds__(256) void w_proto(const float* x, float* proto,
        short* Phi, float* es, double* pninv) { stage_proto(x, proto, Phi, es, pninv); }
__global__ __launch_bounds__(256) void w_gemm(const float* x, const short* Bt,
        float* Sd, float* nq2, int do_ssq) { gemm_stage(x, Bt, Sd, nq2, do_ssq != 0); }
__global__ __launch_bounds__(256) void w_argmax(const float* S, const float* nq2,
        float* coef, float* invq, int* pos, int* ccnt, int* clist, int* rcnt, int* rlist) {
    stage_argmax(S, nq2, coef, invq, pos, ccnt, clist, rcnt, rlist);
}
__global__ __launch_bounds__(256) void w_refine(const float* x, const float* proto,
        const double* pninv, const float* S, const float* invq, float* coef,
        const int* pos, int* ccnt, int* clist, const int* rcnt, const int* rlist) {
    stage_refine(x, proto, pninv, S, invq, coef, pos, ccnt, clist, rcnt, rlist);
}
__global__ __launch_bounds__(256) void w_adapt(const float* x, const float* coef,
        const int* ccnt, const int* clist, float* APpart) {
    stage_adapt(x, coef, ccnt, clist, APpart);
}
__global__ __launch_bounds__(256) void w_apnorm(const float* APpart, const float* proto,
        const float* es, short* APhi) { stage_apnorm(APpart, proto, es, APhi); }
__global__ __launch_bounds__(256) void w_scale(const float* Ored, const float* invq,
        const float* tao, float* out) { stage_scale(Ored, invq, tao, out); }

extern "C" void kernel_launch(void* const* d_in, const int* in_sizes, int n_in,
                              void* d_out, int out_size, void* d_ws, size_t ws_size,
                              hipStream_t stream) {
    const float* x   = (const float*)d_in[0];
    const float* tao = (const float*)d_in[1];
    char* ws = (char*)d_ws;
    float* out = (float*)d_out;

    float*  nq2    = (float*) (ws + OFF_NQ2);
    float*  es     = (float*) (ws + OFF_ES);
    float*  invq   = (float*) (ws + OFF_INVQ);
    int*    pos    = (int*)   (ws + OFF_POS);
    float*  coef   = (float*) (ws + OFF_COEF);
    int*    rcnt   = (int*)   (ws + OFF_RCNT);
    int*    ccnt   = (int*)   (ws + OFF_CCNT);
    int*    rlist  = (int*)   (ws + OFF_RLIST);
    int*    clist  = (int*)   (ws + OFF_CLIST);
    double* pninv  = (double*)(ws + OFF_PNINV);
    float*  proto  = (float*) (ws + OFF_PROTO);
    short*  Phi    = (short*) (ws + OFF_PHI);
    short*  APhi   = (short*) (ws + OFF_APHI);
    float*  Sred   = (float*) (ws + OFF_SRED);
    float*  Ored   = (float*) (ws + OFF_ORED);
    float*  APpart = (float*) (ws + OFF_APPART);

    hipMemsetAsync(ws, 0, ZERO_BYTES, stream);                 // rcnt/ccnt/nq2
    hipMemsetAsync(ws + OFF_SRED, 0, 2u * 3383296u, stream);   // Sred + Ored

    // cooperative path: size grid from REAL occupancy (no launch_bounds gamble)
    int occ = 0;
    hipError_t oe = hipOccupancyMaxActiveBlocksPerMultiprocessor(
            &occ, (const void*)mega, 256, 0);
    if (oe == hipSuccess && occ >= 1) {
        int grid = occ * 256;                  // 256 CUs on MI355X
        if (grid > 1024) grid = 1024;          // no stage needs more than 1600 vb
        void* kargs[] = { (void*)&x, (void*)&tao, (void*)&out, (void*)&ws };
        hipError_t le = hipLaunchCooperativeKernel((const void*)mega,
                dim3(grid), dim3(256), kargs, 0, stream);
        if (le == hipSuccess) return;
    }

    // fallback: the proven round-2 multi-kernel chain (identical stage bodies)
    w_proto <<<NPAD, 256, 0, stream>>>(x, proto, Phi, es, pninv);
    w_gemm  <<<944,  256, 0, stream>>>(x, Phi, Sred, nq2, 1);
    w_argmax<<<30,   256, 0, stream>>>(Sred, nq2, coef, invq, pos, ccnt, clist, rcnt, rlist);
    w_refine<<<512,  256, 0, stream>>>(x, proto, pninv, Sred, invq, coef, pos, ccnt, clist, rcnt, rlist);
    w_adapt <<<1600, 256, 0, stream>>>(x, coef, ccnt, clist, APpart);
    w_apnorm<<<NPAD, 256, 0, stream>>>(APpart, proto, es, APhi);
    w_gemm  <<<944,  256, 0, stream>>>(x, APhi, Ored, nq2, 0);
    w_scale <<<733,  256, 0, stream>>>(Ored, invq, tao, out);
}

// Round 7
// 339.301 us; speedup vs baseline: 1.1591x; 1.1150x over previous
//
#include <hip/hip_runtime.h>
#include <hip/hip_bf16.h>
#include <math.h>

// Problem constants (fixed dataset: n=100, k=5, q=75, d=4096)
#define NQUERY 7500
#define NCLS   100
#define DIM    4096
#define KQ     75
#define KSUP   5
#define RPC    80        // rows per class in x = k+q
#define MPAD   7552      // 472 m-tiles * 16
#define NPAD   112       // 7 n-tiles * 16
#define CAPQ   256
#define RCAP   2048
#define EPSF   1e-8f

typedef __attribute__((ext_vector_type(8))) short bf16x8;
typedef __attribute__((ext_vector_type(4))) short s16x4;
typedef __attribute__((ext_vector_type(4))) float f32x4;

__device__ __forceinline__ int xrow_of_query(int j) {
    return (j / KQ) * RPC + KSUP + (j % KQ);
}
__device__ __forceinline__ short bf16t(float x) {       // truncate fp32 -> bf16 bits
    union { float f; unsigned u; } v; v.f = x;
    return (short)(v.u >> 16);
}
// async global->LDS, 16 B per lane: per-lane SOURCE, wave-uniform LDS base
__device__ __forceinline__ void gload_lds16(const short* g, short* l) {
    __builtin_amdgcn_global_load_lds(
        (const __attribute__((address_space(1))) unsigned int*)g,
        (__attribute__((address_space(3))) unsigned int*)l, 16, 0, 0);
}
// tile-layout offset for class-column c, dim index i:
// [nt][kstep][kq][lm][8] with nt=c>>4, lm=c&15, kstep=i>>5, kq=(i>>3)&3, e=i&7
__device__ __forceinline__ size_t tile_off(int nt, int lm, int i) {
    return (((size_t)(nt * 128 + (i >> 5)) * 4 + ((i >> 3) & 3)) * 16 + lm) * 8 + (i & 7);
}

// ---------------- K1: fused proto: mean -> norm (fp64) -> Phi tile layout + es + pninv
__global__ __launch_bounds__(256) void k_proto(const float* __restrict__ x,
        float* __restrict__ proto, short* __restrict__ Phi, float* __restrict__ es,
        double* __restrict__ pninv) {
    const int c = blockIdx.x, t = threadIdx.x;
    const int nt = c >> 4, lm = c & 15;
    if (c >= NCLS) {
        for (int g = t; g < 512; g += 256) {
            const int kstep = g >> 2, kq = g & 3;
            size_t o = (((size_t)(nt * 128 + kstep) * 4 + kq) * 16 + lm) * 8;
            bf16x8 z = {0,0,0,0,0,0,0,0};
            *(bf16x8*)(Phi + o) = z;
        }
        if (t == 0) es[c] = 0.f;
        return;
    }
    __shared__ double red[4];
    __shared__ float s_inv;
    const float* b0 = x + (size_t)(c * RPC) * DIM;
    float v[16];
    double ssq = 0.0;
#pragma unroll
    for (int p = 0; p < 4; ++p) {
        const int i = p * 1024 + t * 4;
        f32x4 s = {0.f, 0.f, 0.f, 0.f};
#pragma unroll
        for (int r = 0; r < KSUP; ++r)
            s += *(const f32x4*)(b0 + (size_t)r * DIM + i);
        s = s / 5.0f;
        *(f32x4*)&v[p*4] = s;
        *(f32x4*)(proto + (size_t)c*DIM + i) = s;
        ssq += (double)s[0]*s[0] + (double)s[1]*s[1]
             + (double)s[2]*s[2] + (double)s[3]*s[3];
    }
    for (int o = 32; o; o >>= 1) ssq += __shfl_down(ssq, o);
    if ((t & 63) == 0) red[t >> 6] = ssq;
    __syncthreads();
    if (t == 0) {
        double dtot = red[0] + red[1] + red[2] + red[3];
        pninv[c] = 1.0 / sqrt(dtot);
        float tot = (float)dtot;
        float inv = 1.f / fmaxf(sqrtf(tot), EPSF);
        s_inv = inv;
        es[c] = expf(tot * inv * inv);
    }
    __syncthreads();
    const float inv = s_inv;
#pragma unroll
    for (int p = 0; p < 4; ++p) {
        const int i = p * 1024 + t * 4;
        s16x4 h;
#pragma unroll
        for (int e = 0; e < 4; ++e) h[e] = bf16t(v[p*4+e] * inv);
        *(s16x4*)(Phi + tile_off(nt, lm, i)) = h;
    }
}

// ---------------- K2/K8: persistent-B streaming GEMM.
// ROUND-6: block (g,kz) stages its 56 KB B-chunk ONCE via global_load_lds
// (one barrier, read-only after), then its 4 waves sweep m-tiles
// mt = g + 32*(w + 4*p), streaming 16 KB A-batches double-buffered 2 tiles
// deep (32 KB in flight/wave). B off the VMEM path entirely -> A saturates HBM.
// grid (32,16) = 512 blocks = exactly 2/CU at 56 KB LDS.
template<bool SSQ>
__global__ __launch_bounds__(256) void k_gemm(const float* __restrict__ x,
        const short* __restrict__ Bt, float* __restrict__ Sd, float* __restrict__ nq2) {
    __shared__ short sbuf[7 * 8 * 512];   // [nt][s][512] = 56 KB
    const int g = blockIdx.x, kz = blockIdx.y;
    const int w = threadIdx.x >> 6, lane = threadIdx.x & 63;
    const int lm = lane & 15, kq = lane >> 4;
    const int ks0 = kz * 8;

    // stage B-chunk: 56 x 1KB pieces, 14 per wave
#pragma unroll
    for (int p = 0; p < 14; ++p) {
        const int idx = w * 14 + p;           // = nt*8 + s
        const short* gsrc = Bt + (((size_t)((idx >> 3) * 128 + ks0 + (idx & 7))) << 9) + lane * 8;
        gload_lds16(gsrc, sbuf + ((size_t)idx << 9));
    }

    const int mt0 = g + 32 * w;
    const int mt1 = g + 32 * (w + 4);
    const int mt2 = g + 32 * (w + 8);
    const int mt3 = g + 32 * (w + 12);
    const bool v0 = mt0 < 472, v1 = mt1 < 472, v2 = mt2 < 472, v3 = mt3 < 472;

    // A pointers (row = mt*16+lm, dims kz*256 + kq*8 ..)
    auto apt = [&](int mt) {
        const int j = mt * 16 + lm;
        const int jc = j < NQUERY ? j : NQUERY - 1;
        return x + (size_t)xrow_of_query(jc) * DIM + kz * 256 + kq * 8;
    };

    f32x4 A0[16], A1[16];
#define LOADA(buf, mt) do { \
        const float* pa_ = apt(mt); \
        _Pragma("unroll") \
        for (int s_ = 0; s_ < 8; ++s_) { \
            buf[s_*2]   = *(const f32x4*)(pa_ + s_*32); \
            buf[s_*2+1] = *(const f32x4*)(pa_ + s_*32 + 4); \
        } } while (0)

    if (v0) LOADA(A0, mt0);
    if (v1) LOADA(A1, mt1);
    __syncthreads();   // B staged (also drains A0/A1 issues; they're used next)

#define COMPUTE(buf, mt) do { \
        f32x4 acc_[7]; \
        _Pragma("unroll") \
        for (int nt_ = 0; nt_ < 7; ++nt_) acc_[nt_] = (f32x4){0.f,0.f,0.f,0.f}; \
        float ssq_ = 0.f; \
        _Pragma("unroll") \
        for (int s_ = 0; s_ < 8; ++s_) { \
            float f_[8] = {buf[s_*2][0],buf[s_*2][1],buf[s_*2][2],buf[s_*2][3], \
                           buf[s_*2+1][0],buf[s_*2+1][1],buf[s_*2+1][2],buf[s_*2+1][3]}; \
            bf16x8 ah_; \
            _Pragma("unroll") \
            for (int e_ = 0; e_ < 8; ++e_) { \
                if (SSQ) ssq_ += f_[e_] * f_[e_]; \
                ah_[e_] = bf16t(f_[e_]); \
            } \
            _Pragma("unroll") \
            for (int nt_ = 0; nt_ < 7; ++nt_) { \
                const bf16x8 bh_ = *(const bf16x8*)(sbuf + (((size_t)(nt_*8 + s_)) << 9) + lane*8); \
                acc_[nt_] = __builtin_amdgcn_mfma_f32_16x16x32_bf16(ah_, bh_, acc_[nt_], 0, 0, 0); \
            } \
        } \
        if (SSQ) { \
            ssq_ += __shfl_xor(ssq_, 16); ssq_ += __shfl_xor(ssq_, 32); \
            const int j_ = (mt) * 16 + lm; \
            if (kq == 0 && j_ < NQUERY) atomicAdd(&nq2[j_], ssq_); \
        } \
        float* sp_ = Sd + (size_t)((mt) * 16) * NPAD; \
        _Pragma("unroll") \
        for (int nt_ = 0; nt_ < 7; ++nt_) \
            _Pragma("unroll") \
            for (int r_ = 0; r_ < 4; ++r_) \
                atomicAdd(&sp_[(size_t)(kq * 4 + r_) * NPAD + nt_ * 16 + lm], acc_[nt_][r_]); \
    } while (0)

    if (v0) COMPUTE(A0, mt0);
    if (v2) LOADA(A0, mt2);
    if (v1) COMPUTE(A1, mt1);
    if (v3) LOADA(A1, mt3);
    if (v2) COMPUTE(A0, mt2);
    if (v3) COMPUTE(A1, mt3);
#undef LOADA
#undef COMPUTE
}

// ---------------- K3: argmax/top2 + invq + coef + per-class lists + refine-list
__global__ __launch_bounds__(256) void k_argmax(const float* __restrict__ S,
        const float* __restrict__ nq2, float* __restrict__ coef, float* __restrict__ invq,
        int* __restrict__ pos, int* __restrict__ ccnt, int* __restrict__ cls_list,
        int* __restrict__ rcnt, int* __restrict__ rlist) {
    const int j = blockIdx.x * 256 + threadIdx.x;
    if (j >= NQUERY) return;
    const float* row = S + (size_t)j * NPAD;
    float m1 = -1e30f, m2 = -1e30f;
    int i1 = 0, i2 = 0;
    for (int c = 0; c < NCLS; ++c) {
        float v = row[c];
        if (v > m1) { m2 = m1; i2 = i1; m1 = v; i1 = c; }
        else if (v > m2) { m2 = v; i2 = c; }
    }
    const float inv = 1.f / fmaxf(sqrtf(nq2[j]), EPSF);
    invq[j] = inv;
    coef[j] = expf(m1 * inv);
    const int p = atomicAdd(&ccnt[i1], 1);
    if (p < CAPQ) { cls_list[i1 * CAPQ + p] = j; pos[j] = p; }
    else pos[j] = -1;
    if ((m1 - m2) * inv < 5e-4f) {     // bf16-hi gap noise sigma ~5e-5 -> ~10 sigma
        int rp = atomicAdd(rcnt, 1);
        if (rp < RCAP) rlist[rp] = j | (i1 << 13) | (i2 << 20);
    }
}

// ---------------- K4: fp64 refinement via proto dot (query norm cancels; pninv precomputed)
__global__ __launch_bounds__(256) void k_refine(const float* __restrict__ x,
        const float* __restrict__ proto, const double* __restrict__ pninv,
        const float* __restrict__ S, const float* __restrict__ invq,
        float* __restrict__ coef, const int* __restrict__ pos,
        int* __restrict__ ccnt, int* __restrict__ cls_list,
        const int* __restrict__ rcnt, const int* __restrict__ rlist) {
    const int cnt = min(*rcnt, RCAP);
    const int t = threadIdx.x;
    __shared__ double red1[4], red2[4];
    for (int e = blockIdx.x; e < cnt; e += gridDim.x) {
        const int pk = rlist[e];
        const int j = pk & 8191, c1 = (pk >> 13) & 127, c2 = (pk >> 20) & 127;
        const float* xq = x + (size_t)xrow_of_query(j) * DIM;
        const float* p1 = proto + (size_t)c1 * DIM;
        const float* p2 = proto + (size_t)c2 * DIM;
        double d1 = 0.0, d2 = 0.0;
        for (int i = t; i < DIM; i += 256) {
            const double qv = (double)xq[i];
            d1 += (double)p1[i] * qv;
            d2 += (double)p2[i] * qv;
        }
        for (int o = 32; o; o >>= 1) { d1 += __shfl_down(d1, o); d2 += __shfl_down(d2, o); }
        if ((t & 63) == 0) { red1[t >> 6] = d1; red2[t >> 6] = d2; }
        __syncthreads();
        if (t == 0) {
            const double cos1 = (red1[0]+red1[1]+red1[2]+red1[3]) * pninv[c1];
            const double cos2 = (red2[0]+red2[1]+red2[2]+red2[3]) * pninv[c2];
            const int win = (cos2 > cos1 || (cos2 == cos1 && c2 < c1)) ? c2 : c1;
            if (win != c1) {
                coef[j] = expf(S[(size_t)j * NPAD + win] * invq[j]);
                const int pj = pos[j];
                if (pj >= 0) cls_list[c1 * CAPQ + pj] = -1;   // tombstone
                const int np = atomicAdd(&ccnt[c2], 1);
                if (np < CAPQ) cls_list[c2 * CAPQ + np] = j;
            }
        }
        __syncthreads();   // red[] reuse across grid-stride iterations
    }
}

// ---------------- K6: adapted-proto partial scatter sum (grid 8 x NCLS x 4)
__global__ __launch_bounds__(128) void k_adapt(const float* __restrict__ x,
        const float* __restrict__ coef, const int* __restrict__ cls_cnt,
        const int* __restrict__ cls_list, float* __restrict__ APpart) {
    __shared__ int   s_j[CAPQ];
    __shared__ float s_cf[CAPQ];
    const int cx = blockIdx.x, c = blockIdx.y, sl = blockIdx.z;
    const int n = min(cls_cnt[c], CAPQ);
    for (int e = threadIdx.x; e < n; e += 128) {
        const int j = cls_list[c * CAPQ + e];
        s_j[e] = j;
        s_cf[e] = (j >= 0) ? coef[j] : 0.f;
    }
    __syncthreads();
    const int i0 = cx * 512 + threadIdx.x * 4;
    f32x4 acc = {0.f, 0.f, 0.f, 0.f};
    for (int e = sl; e < n; e += 4) {
        const int j = s_j[e];
        if (j >= 0) {
            const float cf = s_cf[e];
            const f32x4 v = *(const f32x4*)(x + (size_t)xrow_of_query(j) * DIM + i0);
            acc += v * cf;
        }
    }
    *(f32x4*)(APpart + (size_t)sl * NCLS * DIM + (size_t)c * DIM + i0) = acc;
}

// ---------------- K7: fused apnorm: sum 4 slices + es*proto -> norm -> APhi tiles
__global__ __launch_bounds__(256) void k_apnorm(const float* __restrict__ APpart,
        const float* __restrict__ proto, const float* __restrict__ es,
        short* __restrict__ APhi) {
    const int c = blockIdx.x, t = threadIdx.x;
    const int nt = c >> 4, lm = c & 15;
    if (c >= NCLS) {
        for (int g = t; g < 512; g += 256) {
            const int kstep = g >> 2, kq = g & 3;
            size_t o = (((size_t)(nt * 128 + kstep) * 4 + kq) * 16 + lm) * 8;
            bf16x8 z = {0,0,0,0,0,0,0,0};
            *(bf16x8*)(APhi + o) = z;
        }
        return;
    }
    __shared__ float red[4];
    __shared__ float s_inv;
    const float e0 = es[c];
    float v[16];
    float ssq = 0.f;
#pragma unroll
    for (int p = 0; p < 4; ++p) {
        const int i = p * 1024 + t * 4;
        f32x4 s = {0.f, 0.f, 0.f, 0.f};
#pragma unroll
        for (int sl = 0; sl < 4; ++sl)
            s += *(const f32x4*)(APpart + (size_t)sl * NCLS * DIM + (size_t)c * DIM + i);
        f32x4 pr = *(const f32x4*)(proto + (size_t)c*DIM + i);
        s += pr * e0;
        *(f32x4*)&v[p*4] = s;
        ssq += s[0]*s[0] + s[1]*s[1] + s[2]*s[2] + s[3]*s[3];
    }
    for (int o = 32; o; o >>= 1) ssq += __shfl_down(ssq, o);
    if ((t & 63) == 0) red[t >> 6] = ssq;
    __syncthreads();
    if (t == 0) {
        float tot = red[0] + red[1] + red[2] + red[3];
        s_inv = 1.f / fmaxf(sqrtf(tot), EPSF);
    }
    __syncthreads();
    const float inv = s_inv;
#pragma unroll
    for (int p = 0; p < 4; ++p) {
        const int i = p * 1024 + t * 4;
        s16x4 h;
#pragma unroll
        for (int e = 0; e < 4; ++e) h[e] = bf16t(v[p*4+e] * inv);
        *(s16x4*)(APhi + tile_off(nt, lm, i)) = h;
    }
}

// ---------------- K8b: out[j,c<100] = tao * invq[j] * Ored[j,c]
__global__ __launch_bounds__(256) void k_scale(const float* __restrict__ Ored,
        const float* __restrict__ invq, const float* __restrict__ tao,
        float* __restrict__ out) {
    const int idx = blockIdx.x * 256 + threadIdx.x;   // < 187500
    if (idx >= NQUERY * 25) return;
    const int j = idx / 25, c4 = (idx % 25) * 4;
    const f32x4 s = *(const f32x4*)(Ored + (size_t)j * NPAD + c4);
    const float sc = tao[0] * invq[j];
    *(f32x4*)(out + (size_t)j * NCLS + c4) = s * sc;
}

// ---------------- workspace layout (bytes)
#define OFF_RCNT   0u
#define OFF_CCNT   256u
#define OFF_NQ2    1792u        // 30000
#define ZERO_BYTES 32768u
#define OFF_ES     32768u       // 448
#define OFF_INVQ   33280u       // 30000
#define OFF_POS    63488u       // 30000
#define OFF_COEF   93696u       // 30000
#define OFF_RLIST  123904u      // 8192
#define OFF_CLIST  132096u      // 102400
#define OFF_PNINV  234496u      // 800 (doubles)
#define OFF_PROTO  235520u      // 1,638,400
#define OFF_PHI    1873920u     // 917,504 (tile layout)
#define OFF_APHI   2791424u     // 917,504
#define OFF_SRED   3708928u     // 3,383,296 (atomic accumulator, GEMM1)
#define OFF_ORED   7092224u     // 3,383,296 (atomic accumulator, GEMM2)
#define OFF_APPART 10475520u    // 4 x 1,638,400

extern "C" void kernel_launch(void* const* d_in, const int* in_sizes, int n_in,
                              void* d_out, int out_size, void* d_ws, size_t ws_size,
                              hipStream_t stream) {
    const float* x   = (const float*)d_in[0];
    const float* tao = (const float*)d_in[1];
    char* ws = (char*)d_ws;

    int*    rcnt   = (int*)   (ws + OFF_RCNT);
    int*    ccnt   = (int*)   (ws + OFF_CCNT);
    float*  nq2    = (float*) (ws + OFF_NQ2);
    float*  es     = (float*) (ws + OFF_ES);
    float*  invq   = (float*) (ws + OFF_INVQ);
    int*    pos    = (int*)   (ws + OFF_POS);
    float*  coef   = (float*) (ws + OFF_COEF);
    int*    rlist  = (int*)   (ws + OFF_RLIST);
    int*    clist  = (int*)   (ws + OFF_CLIST);
    double* pninv  = (double*)(ws + OFF_PNINV);
    float*  proto  = (float*) (ws + OFF_PROTO);
    short*  Phi    = (short*) (ws + OFF_PHI);
    short*  APhi   = (short*) (ws + OFF_APHI);
    float*  Sred   = (float*) (ws + OFF_SRED);
    float*  Ored   = (float*) (ws + OFF_ORED);
    float*  APpart = (float*) (ws + OFF_APPART);

    hipMemsetAsync(ws, 0, ZERO_BYTES, stream);                 // rcnt/ccnt/nq2
    hipMemsetAsync(ws + OFF_SRED, 0, 2u * 3383296u, stream);   // Sred + Ored

    k_proto <<<NPAD, 256, 0, stream>>>(x, proto, Phi, es, pninv);
    k_gemm<true> <<<dim3(32, 16), 256, 0, stream>>>(x, Phi, Sred, nq2);
    k_argmax <<<30, 256, 0, stream>>>(Sred, nq2, coef, invq, pos, ccnt, clist, rcnt, rlist);
    k_refine <<<512, 256, 0, stream>>>(x, proto, pninv, Sred, invq, coef, pos, ccnt, clist, rcnt, rlist);
    k_adapt  <<<dim3(8, NCLS, 4), 128, 0, stream>>>(x, coef, ccnt, clist, APpart);
    k_apnorm <<<NPAD, 256, 0, stream>>>(APpart, proto, es, APhi);
    k_gemm<false><<<dim3(32, 16), 256, 0, stream>>>(x, APhi, Ored, nq2);
    k_scale  <<<733, 256, 0, stream>>>(Ored, invq, tao, (float*)d_out);
}

// Round 8
// 302.663 us; speedup vs baseline: 1.2994x; 1.1211x over previous
//
#include <hip/hip_runtime.h>
#include <hip/hip_bf16.h>
#include <math.h>

// Problem constants (fixed dataset: n=100, k=5, q=75, d=4096)
#define NQUERY 7500
#define NCLS   100
#define DIM    4096
#define KQ     75
#define KSUP   5
#define RPC    80        // rows per class in x = k+q
#define MPAD   7552      // 472 m-tiles * 16
#define NPAD   112       // 7 n-tiles * 16
#define CAPQ   256
#define RCAP   2048
#define EPSF   1e-8f
#define SELEM  845824    // MPAD * NPAD

typedef __attribute__((ext_vector_type(8))) short bf16x8;
typedef __attribute__((ext_vector_type(4))) short s16x4;
typedef __attribute__((ext_vector_type(4))) float f32x4;

__device__ __forceinline__ int xrow_of_query(int j) {
    return (j / KQ) * RPC + KSUP + (j % KQ);
}
__device__ __forceinline__ short bf16t(float x) {       // truncate fp32 -> bf16 bits
    union { float f; unsigned u; } v; v.f = x;
    return (short)(v.u >> 16);
}
// async global->LDS, 16 B per lane: per-lane SOURCE, wave-uniform LDS base
__device__ __forceinline__ void gload_lds16(const short* g, short* l) {
    __builtin_amdgcn_global_load_lds(
        (const __attribute__((address_space(1))) unsigned int*)g,
        (__attribute__((address_space(3))) unsigned int*)l, 16, 0, 0);
}
// tile-layout offset for class-column c, dim index i:
// [nt][kstep][kq][lm][8] with nt=c>>4, lm=c&15, kstep=i>>5, kq=(i>>3)&3, e=i&7
__device__ __forceinline__ size_t tile_off(int nt, int lm, int i) {
    return (((size_t)(nt * 128 + (i >> 5)) * 4 + ((i >> 3) & 3)) * 16 + lm) * 8 + (i & 7);
}

// ---------------- K1: fused proto: mean -> norm (fp64) -> Phi tile layout + es + pninv
__global__ __launch_bounds__(256) void k_proto(const float* __restrict__ x,
        float* __restrict__ proto, short* __restrict__ Phi, float* __restrict__ es,
        double* __restrict__ pninv) {
    const int c = blockIdx.x, t = threadIdx.x;
    const int nt = c >> 4, lm = c & 15;
    if (c >= NCLS) {
        for (int g = t; g < 512; g += 256) {
            const int kstep = g >> 2, kq = g & 3;
            size_t o = (((size_t)(nt * 128 + kstep) * 4 + kq) * 16 + lm) * 8;
            bf16x8 z = {0,0,0,0,0,0,0,0};
            *(bf16x8*)(Phi + o) = z;
        }
        if (t == 0) es[c] = 0.f;
        return;
    }
    __shared__ double red[4];
    __shared__ float s_inv;
    const float* b0 = x + (size_t)(c * RPC) * DIM;
    float v[16];
    double ssq = 0.0;
#pragma unroll
    for (int p = 0; p < 4; ++p) {
        const int i = p * 1024 + t * 4;
        f32x4 s = {0.f, 0.f, 0.f, 0.f};
#pragma unroll
        for (int r = 0; r < KSUP; ++r)
            s += *(const f32x4*)(b0 + (size_t)r * DIM + i);
        s = s / 5.0f;
        *(f32x4*)&v[p*4] = s;
        *(f32x4*)(proto + (size_t)c*DIM + i) = s;
        ssq += (double)s[0]*s[0] + (double)s[1]*s[1]
             + (double)s[2]*s[2] + (double)s[3]*s[3];
    }
    for (int o = 32; o; o >>= 1) ssq += __shfl_down(ssq, o);
    if ((t & 63) == 0) red[t >> 6] = ssq;
    __syncthreads();
    if (t == 0) {
        double dtot = red[0] + red[1] + red[2] + red[3];
        pninv[c] = 1.0 / sqrt(dtot);
        float tot = (float)dtot;
        float inv = 1.f / fmaxf(sqrtf(tot), EPSF);
        s_inv = inv;
        es[c] = expf(tot * inv * inv);
    }
    __syncthreads();
    const float inv = s_inv;
#pragma unroll
    for (int p = 0; p < 4; ++p) {
        const int i = p * 1024 + t * 4;
        s16x4 h;
#pragma unroll
        for (int e = 0; e < 4; ++e) h[e] = bf16t(v[p*4+e] * inv);
        *(s16x4*)(Phi + tile_off(nt, lm, i)) = h;
    }
}

// ---------------- K2/K8: register-accumulated K=1024-per-wave GEMM.
// ROUND-7: grid (118,4). Each wave owns ONE m-tile for a K-quarter (32 ksteps),
// accumulating in registers across the whole quarter -> epilogue is plain
// stores into 4 Part slices (no atomics, 13.5 MB vs 54 MB). B streamed as
// eight 4-kstep chunks through a 2x28KB LDS double-buffer (one barrier/chunk);
// A register-prefetched one chunk ahead. Fully unrolled so all buffer indices
// are compile-time (no scratch). 472 blocks ~ 2/CU, independent barrier domains.
template<bool SSQ>
__global__ __launch_bounds__(256) void k_gemm(const float* __restrict__ x,
        const short* __restrict__ Bt, float* __restrict__ Part, float* __restrict__ nq2) {
    __shared__ short sbuf[2][28 * 512];   // 2 x 28 KB: [buf][nt*4+s][512]
    const int bx = blockIdx.x, kz = blockIdx.y;
    const int w = threadIdx.x >> 6, lane = threadIdx.x & 63;
    const int lm = lane & 15, kq = lane >> 4;
    const int mt = bx * 4 + w;            // 0..471
    const int j = mt * 16 + lm;
    const int jc = j < NQUERY ? j : NQUERY - 1;
    const float* pa = x + (size_t)xrow_of_query(jc) * DIM + kq * 8;
    const int ks0 = kz * 32;              // this block's 32 ksteps (K=1024)

    f32x4 acc[7];
#pragma unroll
    for (int nt = 0; nt < 7; ++nt) acc[nt] = (f32x4){0.f,0.f,0.f,0.f};
    float ssq = 0.f;
    f32x4 Ar0[8], Ar1[8];                 // A chunk double-buffer (named: static idx)

#define STAGE(c_, b_) do { \
        _Pragma("unroll") \
        for (int p_ = 0; p_ < 7; ++p_) { \
            const int idx_ = w * 7 + p_;               /* = nt*4 + s */ \
            const int nt_ = idx_ >> 2, s_ = idx_ & 3; \
            const short* gsrc_ = Bt + (((size_t)(nt_ * 128 + ks0 + (c_) * 4 + s_)) << 9) + lane * 8; \
            gload_lds16(gsrc_, &sbuf[b_][idx_ << 9]); \
        } } while (0)

#define LOADA(c_, buf_) do { \
        _Pragma("unroll") \
        for (int s_ = 0; s_ < 4; ++s_) { \
            buf_[s_*2]   = *(const f32x4*)(pa + (size_t)(ks0 + (c_)*4 + s_) * 32); \
            buf_[s_*2+1] = *(const f32x4*)(pa + (size_t)(ks0 + (c_)*4 + s_) * 32 + 4); \
        } } while (0)

#define COMPUTE(b_, buf_) do { \
        _Pragma("unroll") \
        for (int s_ = 0; s_ < 4; ++s_) { \
            float fv_[8] = {buf_[s_*2][0],buf_[s_*2][1],buf_[s_*2][2],buf_[s_*2][3], \
                            buf_[s_*2+1][0],buf_[s_*2+1][1],buf_[s_*2+1][2],buf_[s_*2+1][3]}; \
            bf16x8 ah_; \
            _Pragma("unroll") \
            for (int e_ = 0; e_ < 8; ++e_) { \
                if (SSQ) ssq += fv_[e_] * fv_[e_]; \
                ah_[e_] = bf16t(fv_[e_]); \
            } \
            _Pragma("unroll") \
            for (int nt_ = 0; nt_ < 7; ++nt_) { \
                const bf16x8 bh_ = *(const bf16x8*)(&sbuf[b_][((nt_*4 + s_) << 9) + lane*8]); \
                acc[nt_] = __builtin_amdgcn_mfma_f32_16x16x32_bf16(ah_, bh_, acc[nt_], 0, 0, 0); \
            } \
        } } while (0)

    STAGE(0, 0); LOADA(0, Ar0);
    __syncthreads();
    // c=0..7, cur alternates 0,1; prefetch c+1 into other buffer before compute
    STAGE(1, 1); LOADA(1, Ar1); COMPUTE(0, Ar0); __syncthreads();
    STAGE(2, 0); LOADA(2, Ar0); COMPUTE(1, Ar1); __syncthreads();
    STAGE(3, 1); LOADA(3, Ar1); COMPUTE(0, Ar0); __syncthreads();
    STAGE(4, 0); LOADA(4, Ar0); COMPUTE(1, Ar1); __syncthreads();
    STAGE(5, 1); LOADA(5, Ar1); COMPUTE(0, Ar0); __syncthreads();
    STAGE(6, 0); LOADA(6, Ar0); COMPUTE(1, Ar1); __syncthreads();
    STAGE(7, 1); LOADA(7, Ar1); COMPUTE(0, Ar0); __syncthreads();
    COMPUTE(1, Ar1);
#undef STAGE
#undef LOADA
#undef COMPUTE

    if (SSQ) {
        ssq += __shfl_xor(ssq, 16);
        ssq += __shfl_xor(ssq, 32);
        if (kq == 0 && j < NQUERY) atomicAdd(&nq2[j], ssq);
    }
    float* sp = Part + (size_t)kz * SELEM + (size_t)(mt * 16) * NPAD;
#pragma unroll
    for (int nt = 0; nt < 7; ++nt)
#pragma unroll
        for (int r = 0; r < 4; ++r)
            sp[(size_t)(kq * 4 + r) * NPAD + nt * 16 + lm] = acc[nt][r];
}

// ---------------- K2b: Sred = sum over 4 kz slices
__global__ __launch_bounds__(256) void k_reduce1(const float* __restrict__ Spart,
        float* __restrict__ Sred) {
    const int idx = blockIdx.x * 256 + threadIdx.x;   // < 211456
    const size_t e = (size_t)idx * 4;
    f32x4 s = {0.f, 0.f, 0.f, 0.f};
#pragma unroll
    for (int kz = 0; kz < 4; ++kz)
        s += *(const f32x4*)(Spart + (size_t)kz * SELEM + e);
    *(f32x4*)(Sred + e) = s;
}

// ---------------- K3: argmax/top2 + invq + coef + per-class lists + refine-list
__global__ __launch_bounds__(256) void k_argmax(const float* __restrict__ S,
        const float* __restrict__ nq2, float* __restrict__ coef, float* __restrict__ invq,
        int* __restrict__ pos, int* __restrict__ ccnt, int* __restrict__ cls_list,
        int* __restrict__ rcnt, int* __restrict__ rlist) {
    const int j = blockIdx.x * 256 + threadIdx.x;
    if (j >= NQUERY) return;
    const float* row = S + (size_t)j * NPAD;
    float m1 = -1e30f, m2 = -1e30f;
    int i1 = 0, i2 = 0;
    for (int c = 0; c < NCLS; ++c) {
        float v = row[c];
        if (v > m1) { m2 = m1; i2 = i1; m1 = v; i1 = c; }
        else if (v > m2) { m2 = v; i2 = c; }
    }
    const float inv = 1.f / fmaxf(sqrtf(nq2[j]), EPSF);
    invq[j] = inv;
    coef[j] = expf(m1 * inv);
    const int p = atomicAdd(&ccnt[i1], 1);
    if (p < CAPQ) { cls_list[i1 * CAPQ + p] = j; pos[j] = p; }
    else pos[j] = -1;
    if ((m1 - m2) * inv < 5e-4f) {     // bf16-hi gap noise sigma ~5e-5 -> ~10 sigma
        int rp = atomicAdd(rcnt, 1);
        if (rp < RCAP) rlist[rp] = j | (i1 << 13) | (i2 << 20);
    }
}

// ---------------- K4: fp64 refinement via proto dot (query norm cancels; pninv precomputed)
__global__ __launch_bounds__(256) void k_refine(const float* __restrict__ x,
        const float* __restrict__ proto, const double* __restrict__ pninv,
        const float* __restrict__ S, const float* __restrict__ invq,
        float* __restrict__ coef, const int* __restrict__ pos,
        int* __restrict__ ccnt, int* __restrict__ cls_list,
        const int* __restrict__ rcnt, const int* __restrict__ rlist) {
    const int cnt = min(*rcnt, RCAP);
    const int t = threadIdx.x;
    __shared__ double red1[4], red2[4];
    for (int e = blockIdx.x; e < cnt; e += gridDim.x) {
        const int pk = rlist[e];
        const int j = pk & 8191, c1 = (pk >> 13) & 127, c2 = (pk >> 20) & 127;
        const float* xq = x + (size_t)xrow_of_query(j) * DIM;
        const float* p1 = proto + (size_t)c1 * DIM;
        const float* p2 = proto + (size_t)c2 * DIM;
        double d1 = 0.0, d2 = 0.0;
        for (int i = t; i < DIM; i += 256) {
            const double qv = (double)xq[i];
            d1 += (double)p1[i] * qv;
            d2 += (double)p2[i] * qv;
        }
        for (int o = 32; o; o >>= 1) { d1 += __shfl_down(d1, o); d2 += __shfl_down(d2, o); }
        if ((t & 63) == 0) { red1[t >> 6] = d1; red2[t >> 6] = d2; }
        __syncthreads();
        if (t == 0) {
            const double cos1 = (red1[0]+red1[1]+red1[2]+red1[3]) * pninv[c1];
            const double cos2 = (red2[0]+red2[1]+red2[2]+red2[3]) * pninv[c2];
            const int win = (cos2 > cos1 || (cos2 == cos1 && c2 < c1)) ? c2 : c1;
            if (win != c1) {
                coef[j] = expf(S[(size_t)j * NPAD + win] * invq[j]);
                const int pj = pos[j];
                if (pj >= 0) cls_list[c1 * CAPQ + pj] = -1;   // tombstone
                const int np = atomicAdd(&ccnt[c2], 1);
                if (np < CAPQ) cls_list[c2 * CAPQ + np] = j;
            }
        }
        __syncthreads();   // red[] reuse across grid-stride iterations
    }
}

// ---------------- K6: adapted-proto partial scatter sum (grid 8 x NCLS x 4)
__global__ __launch_bounds__(128) void k_adapt(const float* __restrict__ x,
        const float* __restrict__ coef, const int* __restrict__ cls_cnt,
        const int* __restrict__ cls_list, float* __restrict__ APpart) {
    __shared__ int   s_j[CAPQ];
    __shared__ float s_cf[CAPQ];
    const int cx = blockIdx.x, c = blockIdx.y, sl = blockIdx.z;
    const int n = min(cls_cnt[c], CAPQ);
    for (int e = threadIdx.x; e < n; e += 128) {
        const int j = cls_list[c * CAPQ + e];
        s_j[e] = j;
        s_cf[e] = (j >= 0) ? coef[j] : 0.f;
    }
    __syncthreads();
    const int i0 = cx * 512 + threadIdx.x * 4;
    f32x4 acc = {0.f, 0.f, 0.f, 0.f};
    for (int e = sl; e < n; e += 4) {
        const int j = s_j[e];
        if (j >= 0) {
            const float cf = s_cf[e];
            const f32x4 v = *(const f32x4*)(x + (size_t)xrow_of_query(j) * DIM + i0);
            acc += v * cf;
        }
    }
    *(f32x4*)(APpart + (size_t)sl * NCLS * DIM + (size_t)c * DIM + i0) = acc;
}

// ---------------- K7: fused apnorm: sum 4 slices + es*proto -> norm -> APhi tiles
__global__ __launch_bounds__(256) void k_apnorm(const float* __restrict__ APpart,
        const float* __restrict__ proto, const float* __restrict__ es,
        short* __restrict__ APhi) {
    const int c = blockIdx.x, t = threadIdx.x;
    const int nt = c >> 4, lm = c & 15;
    if (c >= NCLS) {
        for (int g = t; g < 512; g += 256) {
            const int kstep = g >> 2, kq = g & 3;
            size_t o = (((size_t)(nt * 128 + kstep) * 4 + kq) * 16 + lm) * 8;
            bf16x8 z = {0,0,0,0,0,0,0,0};
            *(bf16x8*)(APhi + o) = z;
        }
        return;
    }
    __shared__ float red[4];
    __shared__ float s_inv;
    const float e0 = es[c];
    float v[16];
    float ssq = 0.f;
#pragma unroll
    for (int p = 0; p < 4; ++p) {
        const int i = p * 1024 + t * 4;
        f32x4 s = {0.f, 0.f, 0.f, 0.f};
#pragma unroll
        for (int sl = 0; sl < 4; ++sl)
            s += *(const f32x4*)(APpart + (size_t)sl * NCLS * DIM + (size_t)c * DIM + i);
        f32x4 pr = *(const f32x4*)(proto + (size_t)c*DIM + i);
        s += pr * e0;
        *(f32x4*)&v[p*4] = s;
        ssq += s[0]*s[0] + s[1]*s[1] + s[2]*s[2] + s[3]*s[3];
    }
    for (int o = 32; o; o >>= 1) ssq += __shfl_down(ssq, o);
    if ((t & 63) == 0) red[t >> 6] = ssq;
    __syncthreads();
    if (t == 0) {
        float tot = red[0] + red[1] + red[2] + red[3];
        s_inv = 1.f / fmaxf(sqrtf(tot), EPSF);
    }
    __syncthreads();
    const float inv = s_inv;
#pragma unroll
    for (int p = 0; p < 4; ++p) {
        const int i = p * 1024 + t * 4;
        s16x4 h;
#pragma unroll
        for (int e = 0; e < 4; ++e) h[e] = bf16t(v[p*4+e] * inv);
        *(s16x4*)(APhi + tile_off(nt, lm, i)) = h;
    }
}

// ---------------- K8b: out[j,c<100] = tao * invq[j] * sum_kz Opart (fused reduce)
__global__ __launch_bounds__(256) void k_scale(const float* __restrict__ Opart,
        const float* __restrict__ invq, const float* __restrict__ tao,
        float* __restrict__ out) {
    const int idx = blockIdx.x * 256 + threadIdx.x;   // < 187500
    if (idx >= NQUERY * 25) return;
    const int j = idx / 25, c4 = (idx % 25) * 4;
    const size_t e = (size_t)j * NPAD + c4;
    f32x4 s = {0.f, 0.f, 0.f, 0.f};
#pragma unroll
    for (int kz = 0; kz < 4; ++kz)
        s += *(const f32x4*)(Opart + (size_t)kz * SELEM + e);
    const float sc = tao[0] * invq[j];
    *(f32x4*)(out + (size_t)j * NCLS + c4) = s * sc;
}

// ---------------- workspace layout (bytes)
#define OFF_RCNT   0u
#define OFF_CCNT   256u
#define OFF_NQ2    1792u        // 30000
#define ZERO_BYTES 32768u
#define OFF_ES     32768u       // 448
#define OFF_INVQ   33280u       // 30000
#define OFF_POS    63488u       // 30000
#define OFF_COEF   93696u       // 30000
#define OFF_RLIST  123904u      // 8192
#define OFF_CLIST  132096u      // 102400
#define OFF_PNINV  234496u      // 800 (doubles)
#define OFF_PROTO  235520u      // 1,638,400
#define OFF_PHI    1873920u     // 917,504 (tile layout)
#define OFF_APHI   2791424u     // 917,504
#define OFF_SRED   3708928u     // 3,383,296 (reduced S)
#define OFF_APPART 10475520u    // 4 x 1,638,400
#define OFF_PART   17029120u    // 4 x 3,383,296 (per-kz GEMM slices)

extern "C" void kernel_launch(void* const* d_in, const int* in_sizes, int n_in,
                              void* d_out, int out_size, void* d_ws, size_t ws_size,
                              hipStream_t stream) {
    const float* x   = (const float*)d_in[0];
    const float* tao = (const float*)d_in[1];
    char* ws = (char*)d_ws;

    int*    rcnt   = (int*)   (ws + OFF_RCNT);
    int*    ccnt   = (int*)   (ws + OFF_CCNT);
    float*  nq2    = (float*) (ws + OFF_NQ2);
    float*  es     = (float*) (ws + OFF_ES);
    float*  invq   = (float*) (ws + OFF_INVQ);
    int*    pos    = (int*)   (ws + OFF_POS);
    float*  coef   = (float*) (ws + OFF_COEF);
    int*    rlist  = (int*)   (ws + OFF_RLIST);
    int*    clist  = (int*)   (ws + OFF_CLIST);
    double* pninv  = (double*)(ws + OFF_PNINV);
    float*  proto  = (float*) (ws + OFF_PROTO);
    short*  Phi    = (short*) (ws + OFF_PHI);
    short*  APhi   = (short*) (ws + OFF_APHI);
    float*  Sred   = (float*) (ws + OFF_SRED);
    float*  APpart = (float*) (ws + OFF_APPART);
    float*  Part   = (float*) (ws + OFF_PART);

    hipMemsetAsync(ws, 0, ZERO_BYTES, stream);   // rcnt/ccnt/nq2 only

    k_proto <<<NPAD, 256, 0, stream>>>(x, proto, Phi, es, pninv);
    k_gemm<true> <<<dim3(118, 4), 256, 0, stream>>>(x, Phi, Part, nq2);
    k_reduce1<<<826, 256, 0, stream>>>(Part, Sred);
    k_argmax <<<30, 256, 0, stream>>>(Sred, nq2, coef, invq, pos, ccnt, clist, rcnt, rlist);
    k_refine <<<512, 256, 0, stream>>>(x, proto, pninv, Sred, invq, coef, pos, ccnt, clist, rcnt, rlist);
    k_adapt  <<<dim3(8, NCLS, 4), 128, 0, stream>>>(x, coef, ccnt, clist, APpart);
    k_apnorm <<<NPAD, 256, 0, stream>>>(APpart, proto, es, APhi);
    k_gemm<false><<<dim3(118, 4), 256, 0, stream>>>(x, APhi, Part, nq2);
    k_scale  <<<733, 256, 0, stream>>>(Part, invq, tao, (float*)d_out);
}